// Round 5
// baseline (914.345 us; speedup 1.0000x reference)
//
#include <hip/hip_runtime.h>

typedef unsigned short ushort_t;
typedef __attribute__((ext_vector_type(8))) __bf16 bf16x8;
typedef __attribute__((ext_vector_type(8))) unsigned short ushort8;
typedef __attribute__((ext_vector_type(4))) float floatx4;
typedef __attribute__((ext_vector_type(16))) float floatx16;

#define VN 778
#define KNB 9

__device__ __forceinline__ float bf2f(unsigned short s) {
  union { unsigned int u; float f; } x; x.u = ((unsigned int)s) << 16; return x.f;
}
__device__ __forceinline__ unsigned short f2bf(float f) {
  union { float f; unsigned int u; } x; x.f = f;
  unsigned int r = x.u + 0x7fffu + ((x.u >> 16) & 1u);
  return (unsigned short)(r >> 16);
}

// async global -> LDS, 16B per lane; LDS dest = wave-uniform base + lane*16.
__device__ __forceinline__ void load_lds16(const void* g, void* l) {
  __builtin_amdgcn_global_load_lds(
      (const __attribute__((address_space(1))) unsigned int*)g,
      (__attribute__((address_space(3))) unsigned int*)l, 16, 0, 0);
}

// Bijective XCD-aware swizzle (m204 form): XCD k gets a contiguous wgid range.
__device__ __forceinline__ int xcd_swizzle(int g, int nwg) {
  int q = nwg >> 3, r = nwg & 7;
  int xcd = g & 7, o = g >> 3;
  return (xcd < r ? xcd * (q + 1) : r * (q + 1) + (xcd - r) * q) + o;
}

// ---------------- prologue: occ probabilities, finger ids, wh transpose ----
__global__ void prep_misc(const float* __restrict__ pred_occ,
                          const int* f0, const int* f1, const int* f2,
                          const int* f3, const int* f4,
                          int n0, int n1, int n2, int n3, int n4,
                          const float* __restrict__ wh,
                          float* __restrict__ occ, int* __restrict__ fid,
                          float* __restrict__ whT) {
  int t = threadIdx.x;
  for (int i = t; i < 192 * 5; i += 256) {
    int r = i / 5, f = i % 5;
    float p0 = pred_occ[r * 10 + f];
    float p1 = pred_occ[r * 10 + 5 + f];
    occ[i] = 1.0f / (1.0f + __expf(p1 - p0));  // softmax over 2 classes, class 0
  }
  for (int i = t; i < VN; i += 256) fid[i] = -1;
  __syncthreads();
  const int* fp[5] = {f0, f1, f2, f3, f4};
  int fn[5] = {n0, n1, n2, n3, n4};
  for (int fi = 0; fi < 5; ++fi) {  // sequential: later fingers overwrite
    for (int i = t; i < fn[fi]; i += 256) fid[fp[fi][i]] = fi;
    __syncthreads();
  }
  for (int i = t; i < 3 * 2304; i += 256) {
    int o = i / 2304, k = i % 2304;
    whT[i] = wh[k * 3 + o];
  }
}

// ---------------- weighted view mix: wx[b,v,c] (bf16 out) ------------------
__global__ void wx_kernel(const float* __restrict__ x, const float* __restrict__ occ,
                          const int* __restrict__ fid, ushort_t* __restrict__ wx) {
  int g = blockIdx.x * 256 + threadIdx.x;  // 8-ch chunk id over 64*778*32 (exact)
  int c8 = (g & 31) << 3;
  int bv = g >> 5;
  int b = bv / VN;
  int v = bv - b * VN;
  int f = fid[v];
  float w0 = 1.f, w1 = 1.f, w2 = 1.f;
  if (f >= 0) {
    w0 = occ[b * 5 + f];
    w1 = occ[(64 + b) * 5 + f];
    w2 = occ[(128 + b) * 5 + f];
  }
  float m = fmaxf(w0, fmaxf(w1, w2));
  float e0 = __expf(w0 - m), e1 = __expf(w1 - m), e2 = __expf(w2 - m);
  float inv = 1.0f / (e0 + e1 + e2);
  e0 *= inv; e1 *= inv; e2 *= inv;
  size_t base = (size_t)bv * 256 + c8;
  const size_t V1 = (size_t)64 * VN * 256, V2 = (size_t)128 * VN * 256;
  floatx4 x0a = *(const floatx4*)(x + base);
  floatx4 x0b = *(const floatx4*)(x + base + 4);
  floatx4 x1a = *(const floatx4*)(x + V1 + base);
  floatx4 x1b = *(const floatx4*)(x + V1 + base + 4);
  floatx4 x2a = *(const floatx4*)(x + V2 + base);
  floatx4 x2b = *(const floatx4*)(x + V2 + base + 4);
  ushort8 o;
#pragma unroll
  for (int e = 0; e < 4; ++e) {
    o[e]     = f2bf(e0 * x0a[e] + e1 * x1a[e] + e2 * x2a[e]);
    o[e + 4] = f2bf(e0 * x0b[e] + e1 * x1b[e] + e2 * x2b[e]);
  }
  *(ushort8*)(wx + base) = o;
}

// ---------------- x view-0 f32 -> bf16 copy --------------------------------
__global__ void xcvt_kernel(const float* __restrict__ x, ushort_t* __restrict__ xb) {
  int g = blockIdx.x * 256 + threadIdx.x;
  size_t base = (size_t)g * 8;
  floatx4 fa = *(const floatx4*)(x + base);
  floatx4 fb = *(const floatx4*)(x + base + 4);
  ushort8 o;
#pragma unroll
  for (int e = 0; e < 4; ++e) { o[e] = f2bf(fa[e]); o[e + 4] = f2bf(fb[e]); }
  *(ushort8*)(xb + base) = o;
}

// ---------------- pack W[k][n] (f32) into bf16 MFMA B-fragment order --------
// strip-major: chunk = ((n/32)*(Ktot/16) + k/16)*64 + ((k%16)/8)*32 + (n%32)
__global__ void pack_w(const float* __restrict__ w, ushort_t* __restrict__ wP,
                       int N, int ksn, int total) {
  int chunk = blockIdx.x * 256 + threadIdx.x;
  if (chunk >= total) return;
  int lane = chunk & 63;
  int rest = chunk >> 6;
  int ks = rest % ksn;
  int tn = rest / ksn;
  int n = (tn << 5) + (lane & 31);
  int kb = (ks << 4) + ((lane >> 5) << 3);
  ushort8 o;
#pragma unroll
  for (int j = 0; j < 8; ++j) o[j] = f2bf(w[(size_t)(kb + j) * N + n]);
  *(ushort8*)(wP + (size_t)chunk * 8) = o;
}

// pairwise-interleaved pack for 64n-wide waves: the two 32-n sub-strips of a
// 64-n tile are adjacent per k-step, so a wave's 2 B loads are bp / bp+1024B.
// chunk = (((n/64)*Ktot16 + k/16)*2 + (n%64)/32)*64 + ((k%16)/8)*32 + (n%32)
__global__ void pack_w64(const float* __restrict__ w, ushort_t* __restrict__ wP,
                         int N, int ksn, int total) {
  int chunk = blockIdx.x * 256 + threadIdx.x;
  if (chunk >= total) return;
  int lane = chunk & 63;
  int idx2 = chunk >> 6;
  int sub = idx2 & 1;
  int rest = idx2 >> 1;
  int ks = rest % ksn;
  int tn64 = rest / ksn;
  int n = (tn64 << 6) + (sub << 5) + (lane & 31);
  int kb = (ks << 4) + ((lane >> 5) << 3);
  ushort8 o;
#pragma unroll
  for (int j = 0; j < 8; ++j) o[j] = f2bf(w[(size_t)(kb + j) * N + n]);
  *(ushort8*)(wP + (size_t)chunk * 8) = o;
}

// ---------------- conv0: spiral gathered GEMM (round-0 proven structure) ----
// block = 2 vertices, 512 threads (8 waves); wave tile = 128m(2v x 64b) x 32n.
// 1 B-load per 4 MFMA. A double-buffered in 128-ch phases (2 x 32 KB LDS),
// staged by global_load_lds DMA, swizzle on SOURCE side; ONE barrier per phase.
// MODE 1: wx bf16 + x f32 (f32 phases staged synchronously). MODE 2: wx bf16
// + pre-converted bf16 xb.
template <int CIN, int MODE>
__global__ __launch_bounds__(512, 4) void spiral_gemm(
    const ushort_t* __restrict__ act0, const float* __restrict__ actF,
    const ushort_t* __restrict__ actB, const ushort_t* __restrict__ wP,
    const float* __restrict__ bias, const int* __restrict__ idx,
    ushort_t* __restrict__ out, int NOUT, int nbx) {
  constexpr int H = CIN / 128;       // 128-ch phases per neighbor
  constexpr int P = KNB * H;
  __shared__ __align__(16) ushort_t Alds[2][2048 * 8];   // 2 x 32 KB
  const int wgid = xcd_swizzle(blockIdx.x, gridDim.x);
  const int yb = wgid / nbx;
  const int xb = wgid - yb * nbx;
  const int v0 = xb * 2;
  const int n0 = yb << 8;
  const int tid = threadIdx.x;
  const int lane = tid & 63;
  const int wv = tid >> 6;           // n-strip (0..7)
  const int mlo = lane & 31;
  const int q = lane >> 5;
  const int xm = mlo & 7;
  floatx16 acc0{}, acc1{}, acc2{}, acc3{};
  const int KtotSteps = KNB * (CIN / 16);
  const int tn0 = (n0 >> 5) + wv;
  const ushort_t* bp = wP + (size_t)tn0 * KtotSteps * 512 + lane * 8;
  const int* iv0 = idx + v0 * KNB;
  const int* iv1 = iv0 + KNB;
  const int aoff0 = mlo * 128;
  const int aoff1 = (mlo + 32) * 128;
  const int aoff2 = 8192 + mlo * 128;
  const int aoff3 = 8192 + (mlo + 32) * 128;

  auto dma_stage = [&](int p, ushort_t* buf) {  // bf16 phases only
    const int nbr = p / H, h = p - nbr * H;
    const int nva = iv0[nbr], nvb = iv1[nbr];
#pragma unroll
    for (int it = 0; it < 4; ++it) {
      const int slotb = ((wv << 2) + it) << 6;   // wave-uniform slot base
      const int s = slotb + lane;
      const int vv = s >> 10;
      const int row = (s >> 4) & 63;
      const int ck = (s & 15) ^ (row & 7);       // swizzle on source side
      const int nv = vv ? nvb : nva;
      const ushort_t* src;
      if (MODE == 0) {
        src = act0 + ((size_t)(row * VN + nv)) * CIN + h * 128 + ck * 8;
      } else {
        const ushort_t* basep = (MODE == 1 || h < 2) ? act0 : actB;
        src = basep + ((size_t)(row * VN + nv)) * 256 + (h & 1) * 128 + ck * 8;
      }
      load_lds16(src, buf + (size_t)slotb * 8);
    }
  };
  auto f32_stage = [&](int p, ushort_t* buf) {  // MODE 1, h in {2,3}
    const int nbr = p / H, h = p - nbr * H;
    const int nva = iv0[nbr], nvb = iv1[nbr];
#pragma unroll
    for (int j = 0; j < 4; ++j) {
      const int s = (j << 9) + tid;
      const int vv = s >> 10;
      const int row = (s >> 4) & 63;
      const int ck = (s & 15) ^ (row & 7);
      const int nv = vv ? nvb : nva;
      const float* src = actF + ((size_t)(row * VN + nv)) * 256 + (h - 2) * 128 + ck * 8;
      floatx4 fa = *(const floatx4*)src;
      floatx4 fb = *(const floatx4*)(src + 4);
      ushort8 o;
#pragma unroll
      for (int e = 0; e < 4; ++e) { o[e] = f2bf(fa[e]); o[e + 4] = f2bf(fb[e]); }
      *(ushort8*)(buf + (size_t)s * 8) = o;
    }
  };

  dma_stage(0, Alds[0]);   // phase 0 is always bf16 (h=0)
  __syncthreads();
#pragma unroll 2
  for (int p = 0; p < P; ++p) {
    ushort_t* cur = Alds[p & 1];
    ushort_t* nxt = Alds[(p + 1) & 1];
    const bool have_next = (p + 1 < P);
    const bool next_f32 = (MODE == 1) && (((p + 1) & (H - 1)) >= 2);
    if (have_next && !next_f32) dma_stage(p + 1, nxt);
#pragma unroll
    for (int ks = 0; ks < 8; ++ks) {
      const int cko = ((((ks << 1) + q) ^ xm) << 3);
      bf16x8 a0 = *(const bf16x8*)(cur + aoff0 + cko);
      bf16x8 a1 = *(const bf16x8*)(cur + aoff1 + cko);
      bf16x8 a2 = *(const bf16x8*)(cur + aoff2 + cko);
      bf16x8 a3 = *(const bf16x8*)(cur + aoff3 + cko);
      bf16x8 bv = *(const bf16x8*)bp; bp += 512;
      acc0 = __builtin_amdgcn_mfma_f32_32x32x16_bf16(a0, bv, acc0, 0, 0, 0);
      acc1 = __builtin_amdgcn_mfma_f32_32x32x16_bf16(a1, bv, acc1, 0, 0, 0);
      acc2 = __builtin_amdgcn_mfma_f32_32x32x16_bf16(a2, bv, acc2, 0, 0, 0);
      acc3 = __builtin_amdgcn_mfma_f32_32x32x16_bf16(a3, bv, acc3, 0, 0, 0);
    }
    __syncthreads();   // drains DMA vmcnt; all waves done reading cur
    if (have_next && next_f32) { f32_stage(p + 1, nxt); __syncthreads(); }
  }
  // epilogue: C/D layout col=lane&31 (=n), row=(reg&3)+8*(reg>>2)+4*(lane>>5)
  const int n = n0 + (wv << 5) + mlo;
  const float bn = bias[n];
#pragma unroll
  for (int t = 0; t < 4; ++t) {
    const floatx16 av = (t == 0) ? acc0 : (t == 1) ? acc1 : (t == 2) ? acc2 : acc3;
    const int vcur = v0 + (t >> 1);
    const int bbase = (t & 1) << 5;
#pragma unroll
    for (int r = 0; r < 16; ++r) {
      const int m = (r & 3) + ((r >> 2) << 3) + (q << 2);
      float val = av[r] + bn; val = val > 0.f ? val : 0.f;
      out[((size_t)((bbase + m) * VN + vcur)) * NOUT + n] = f2bf(val);
    }
  }
}

// ---------------- conv1/conv2: 1-vertex spiral GEMM (tail fix) --------------
// block = 1 vertex, 256 threads (4 waves); wave tile = 64m x 64n (4 accs);
// N = 256 covered by 4 waves -> grid = 778 blocks, 4 blocks/CU (LDS 2x16 KB,
// regs 64 AGPR + ~56 VGPR <= 128) -> 16 waves/CU across 4 INDEPENDENT blocks
// and a single-round makespan (778 blocks on 1024 resident slots), fixing the
// old 389-block/512-slot 1.52-round dispatch tail. B comes from the pairwise-
// interleaved pack_w64 panel: the wave's 2 loads per k-step are bp / bp+1KB
// (single address stream, L2-resident 2.36/1.18 MB panel).
template <int CIN>
__global__ __launch_bounds__(256, 4) void spiral_gemm_v1(
    const ushort_t* __restrict__ act, const ushort_t* __restrict__ wP,
    const float* __restrict__ bias, const int* __restrict__ idx,
    ushort_t* __restrict__ out) {
  constexpr int H = CIN / 128;       // 128-ch phases per neighbor
  constexpr int P = KNB * H;
  constexpr int KtotSteps = KNB * (CIN / 16);
  __shared__ __align__(16) ushort_t Alds[2][1024 * 8];   // 2 x 16 KB
  const int v = xcd_swizzle(blockIdx.x, gridDim.x);
  const int tid = threadIdx.x;
  const int lane = tid & 63;
  const int wv = tid >> 6;           // wave id (0..3) = 64-wide n strip
  const int mlo = lane & 31;
  const int q = lane >> 5;
  const int xm = mlo & 7;
  floatx16 c00{}, c01{}, c10{}, c11{};
  const ushort_t* bp = wP + (size_t)wv * KtotSteps * 1024 + lane * 8;
  const int* iv = idx + v * KNB;
  // A-frag element offsets; LDS elem = row*128 + ck*8 (64 rows x 128 ch)
  const int aoff0 = mlo * 128;              // batches 0..31
  const int aoff1 = (mlo + 32) * 128;       // batches 32..63

  auto dma_stage = [&](int p, ushort_t* buf) {
    const int nbr = p / H, h = p - nbr * H;
    const int nv = iv[nbr];
#pragma unroll
    for (int it = 0; it < 4; ++it) {
      const int slotb = ((wv << 2) + it) << 6;   // wave-uniform slot base
      const int s = slotb + lane;                // 0..1023
      const int row = (s >> 4) & 63;
      const int ck = (s & 15) ^ (row & 7);       // swizzle on source side
      const ushort_t* src = act + ((size_t)(row * VN + nv)) * CIN + h * 128 + ck * 8;
      load_lds16(src, buf + (size_t)slotb * 8);
    }
  };

  dma_stage(0, Alds[0]);
  __syncthreads();
#pragma unroll 2
  for (int p = 0; p < P; ++p) {
    ushort_t* cur = Alds[p & 1];
    if (p + 1 < P) dma_stage(p + 1, Alds[(p + 1) & 1]);
#pragma unroll
    for (int ks = 0; ks < 8; ++ks) {
      const int cko = ((((ks << 1) + q) ^ xm) << 3);
      bf16x8 a0 = *(const bf16x8*)(cur + aoff0 + cko);
      bf16x8 a1 = *(const bf16x8*)(cur + aoff1 + cko);
      bf16x8 b0 = *(const bf16x8*)bp;
      bf16x8 b1 = *(const bf16x8*)(bp + 512);
      bp += 1024;
      c00 = __builtin_amdgcn_mfma_f32_32x32x16_bf16(a0, b0, c00, 0, 0, 0);
      c10 = __builtin_amdgcn_mfma_f32_32x32x16_bf16(a1, b0, c10, 0, 0, 0);
      c01 = __builtin_amdgcn_mfma_f32_32x32x16_bf16(a0, b1, c01, 0, 0, 0);
      c11 = __builtin_amdgcn_mfma_f32_32x32x16_bf16(a1, b1, c11, 0, 0, 0);
    }
    __syncthreads();   // drains DMA vmcnt; all waves done reading cur
  }
  // epilogue: C/D layout col=lane&31 (=n), row=(reg&3)+8*(reg>>2)+4*(lane>>5)
  const int nb = (wv << 6) + mlo;
  const float bn0 = bias[nb];
  const float bn1 = bias[nb + 32];
#pragma unroll
  for (int t = 0; t < 4; ++t) {
    const int mi = t >> 1;          // batch half (from a0/a1)
    const int ni = t & 1;           // n half (from b0/b1)
    const floatx16 av = (t == 0) ? c00 : (t == 1) ? c01 : (t == 2) ? c10 : c11;
    const int n = nb + (ni << 5);
    const float bn = ni ? bn1 : bn0;
#pragma unroll
    for (int r = 0; r < 16; ++r) {
      const int m = (r & 3) + ((r >> 2) << 3) + (q << 2) + (mi << 5);
      float val = av[r] + bn; val = val > 0.f ? val : 0.f;
      out[((size_t)(m * VN + v)) * 256 + n] = f2bf(val);
    }
  }
}

// ---------------- head: gathered [64 x 2304] @ [2304 x 3], f32 out ---------
__global__ void head_kernel(const ushort_t* __restrict__ act, const float* __restrict__ whT,
                            const float* __restrict__ bh, const int* __restrict__ idx,
                            float* __restrict__ out) {
  __shared__ __align__(16) ushort_t Alds[64 * 256];
  const int v = xcd_swizzle(blockIdx.x, gridDim.x);
  const int tid = threadIdx.x;
  float a0 = 0.f, a1 = 0.f, a2 = 0.f;
  const int b = tid;  // valid when tid < 64
  const int xm = b & 7;
  for (int nbr = 0; nbr < KNB; ++nbr) {
    const int nv = idx[v * KNB + nbr];
    __syncthreads();
#pragma unroll
    for (int it = 0; it < 8; ++it) {
      int L = it * 256 + tid;
      int bb = L >> 5;
      int jj = L & 31;
      ushort8 val = *(const ushort8*)(act + ((size_t)(bb * VN + nv)) * 256 + (jj << 3));
      int slot = jj ^ (bb & 7);
      *(ushort8*)&Alds[(size_t)(bb * 32 + slot) * 8] = val;
    }
    __syncthreads();
    if (tid < 64) {
      const float* wp = whT + nbr * 256;
#pragma unroll 4
      for (int j = 0; j < 32; ++j) {
        int jj = j ^ xm;
        ushort8 a8 = *(const ushort8*)&Alds[(b * 32 + jj) * 8];
#pragma unroll
        for (int e = 0; e < 8; ++e) {
          float av = bf2f(a8[e]);
          int k = (j << 3) + e;
          a0 += av * wp[k];
          a1 += av * wp[2304 + k];
          a2 += av * wp[4608 + k];
        }
      }
    }
  }
  if (tid < 64) {
    size_t o = ((size_t)(b * VN + v)) * 3;
    out[o + 0] = a0 + bh[0];
    out[o + 1] = a1 + bh[1];
    out[o + 2] = a2 + bh[2];
  }
}

extern "C" void kernel_launch(void* const* d_in, const int* in_sizes, int n_in,
                              void* d_out, int out_size, void* d_ws, size_t ws_size,
                              hipStream_t stream) {
  const float* x        = (const float*)d_in[0];
  const float* pred_occ = (const float*)d_in[1];
  const int* indices    = (const int*)d_in[2];
  const int* f0 = (const int*)d_in[3];
  const int* f1 = (const int*)d_in[4];
  const int* f2 = (const int*)d_in[5];
  const int* f3 = (const int*)d_in[6];
  const int* f4 = (const int*)d_in[7];
  const float* w0 = (const float*)d_in[8];
  const float* b0 = (const float*)d_in[9];
  const float* w1 = (const float*)d_in[10];
  const float* b1 = (const float*)d_in[11];
  const float* w2 = (const float*)d_in[12];
  const float* b2 = (const float*)d_in[13];
  const float* wh = (const float*)d_in[14];
  const float* bh = (const float*)d_in[15];
  float* outp = (float*)d_out;

  char* ws = (char*)d_ws;
  ushort_t* wP0 = (ushort_t*)(ws + 0);         // 512 x 4608 bf16 (4,718,592 B)
  ushort_t* wP1 = (ushort_t*)(ws + 4718592);   // 256 x 4608 bf16 (2,359,296 B)
  ushort_t* wP2 = (ushort_t*)(ws + 7077888);   // 256 x 2304 bf16 (1,179,648 B)
  float* whT    = (float*)(ws + 8257536);      // 3 x 2304 f32
  float* occ    = (float*)(ws + 8285184);      // 192 x 5 f32
  int* fid      = (int*)(ws + 8289024);        // 778 i32
  ushort_t* R0  = (ushort_t*)(ws + 8292352);   // wx, later h2   [64,V,256] 25.5MB
  ushort_t* R1  = (ushort_t*)(ws + 33785856);  // h1, later h3   [64,V,512] 51MB
  ushort_t* XB  = (ushort_t*)(ws + 84772864);  // optional bf16 x view0, 25.5MB
  const bool useXB = (ws_size >= 110266368ull);

  prep_misc<<<1, 256, 0, stream>>>(pred_occ, f0, f1, f2, f3, f4,
                                   in_sizes[3], in_sizes[4], in_sizes[5],
                                   in_sizes[6], in_sizes[7], wh, occ, fid, whT);
  pack_w<<<294912 / 256, 256, 0, stream>>>(w0, wP0, 512, 288, 294912);
  pack_w64<<<147456 / 256, 256, 0, stream>>>(w1, wP1, 256, 288, 147456);
  pack_w64<<<73728 / 256, 256, 0, stream>>>(w2, wP2, 256, 144, 73728);
  if (useXB) xcvt_kernel<<<6224, 256, 0, stream>>>(x, XB);
  wx_kernel<<<6224, 256, 0, stream>>>(x, occ, fid, R0);

  // conv0: [wx | x_view0] (512ch) -> h1 (512ch bf16); 1-D grid 778 = 389x * 2y,
  // XCD swizzle keeps each B half-panel resident in one XCD group's L2.
  if (useXB)
    spiral_gemm<512, 2><<<778, 512, 0, stream>>>(R0, nullptr, XB, wP0, b0,
                                                 indices, R1, 512, 389);
  else
    spiral_gemm<512, 1><<<778, 512, 0, stream>>>(R0, x, nullptr, wP0, b0,
                                                 indices, R1, 512, 389);
  // conv1: h1 (512ch) -> h2 (256ch); 1-vertex blocks, single-round makespan
  spiral_gemm_v1<512><<<778, 256, 0, stream>>>(R1, wP1, b1, indices, R0);
  // conv2: h2 (256ch) -> h3 (256ch)
  spiral_gemm_v1<256><<<778, 256, 0, stream>>>(R0, wP2, b2, indices, R1);
  // head: h3 -> out [64,V,3] f32
  head_kernel<<<VN, 256, 0, stream>>>(R1, whT, bh, indices, outp);
  (void)n_in; (void)out_size;
}

// Round 7
// 809.021 us; speedup vs baseline: 1.1302x; 1.1302x over previous
//
#include <hip/hip_runtime.h>

typedef unsigned short ushort_t;
typedef __attribute__((ext_vector_type(8))) __bf16 bf16x8;
typedef __attribute__((ext_vector_type(8))) unsigned short ushort8;
typedef __attribute__((ext_vector_type(4))) float floatx4;
typedef __attribute__((ext_vector_type(16))) float floatx16;

#define VN 778
#define KNB 9

__device__ __forceinline__ float bf2f(unsigned short s) {
  union { unsigned int u; float f; } x; x.u = ((unsigned int)s) << 16; return x.f;
}
__device__ __forceinline__ unsigned short f2bf(float f) {
  union { float f; unsigned int u; } x; x.f = f;
  unsigned int r = x.u + 0x7fffu + ((x.u >> 16) & 1u);
  return (unsigned short)(r >> 16);
}

// async global -> LDS, 16B per lane; LDS dest = wave-uniform base + lane*16.
__device__ __forceinline__ void load_lds16(const void* g, void* l) {
  __builtin_amdgcn_global_load_lds(
      (const __attribute__((address_space(1))) unsigned int*)g,
      (__attribute__((address_space(3))) unsigned int*)l, 16, 0, 0);
}

// Bijective XCD-aware swizzle (m204 form): XCD k gets a contiguous wgid range.
__device__ __forceinline__ int xcd_swizzle(int g, int nwg) {
  int q = nwg >> 3, r = nwg & 7;
  int xcd = g & 7, o = g >> 3;
  return (xcd < r ? xcd * (q + 1) : r * (q + 1) + (xcd - r) * q) + o;
}

// ---------------- prologue: occ probabilities, finger ids, wh transpose ----
__global__ void prep_misc(const float* __restrict__ pred_occ,
                          const int* f0, const int* f1, const int* f2,
                          const int* f3, const int* f4,
                          int n0, int n1, int n2, int n3, int n4,
                          const float* __restrict__ wh,
                          float* __restrict__ occ, int* __restrict__ fid,
                          float* __restrict__ whT) {
  int t = threadIdx.x;
  for (int i = t; i < 192 * 5; i += 256) {
    int r = i / 5, f = i % 5;
    float p0 = pred_occ[r * 10 + f];
    float p1 = pred_occ[r * 10 + 5 + f];
    occ[i] = 1.0f / (1.0f + __expf(p1 - p0));  // softmax over 2 classes, class 0
  }
  for (int i = t; i < VN; i += 256) fid[i] = -1;
  __syncthreads();
  const int* fp[5] = {f0, f1, f2, f3, f4};
  int fn[5] = {n0, n1, n2, n3, n4};
  for (int fi = 0; fi < 5; ++fi) {  // sequential: later fingers overwrite
    for (int i = t; i < fn[fi]; i += 256) fid[fp[fi][i]] = fi;
    __syncthreads();
  }
  for (int i = t; i < 3 * 2304; i += 256) {
    int o = i / 2304, k = i % 2304;
    whT[i] = wh[k * 3 + o];
  }
}

// ---------------- weighted view mix + fused view-0 bf16 copy ----------------
// wx[b,v,c] (bf16) = softmax-weighted mix of the 3 views; optionally also
// writes xb = bf16(x view-0), fusing the old xcvt pass (saves a 51 MB re-read).
__global__ void wx_kernel(const float* __restrict__ x, const float* __restrict__ occ,
                          const int* __restrict__ fid, ushort_t* __restrict__ wx,
                          ushort_t* __restrict__ xb) {
  int g = blockIdx.x * 256 + threadIdx.x;  // 8-ch chunk id over 64*778*32 (exact)
  int c8 = (g & 31) << 3;
  int bv = g >> 5;
  int b = bv / VN;
  int v = bv - b * VN;
  int f = fid[v];
  float w0 = 1.f, w1 = 1.f, w2 = 1.f;
  if (f >= 0) {
    w0 = occ[b * 5 + f];
    w1 = occ[(64 + b) * 5 + f];
    w2 = occ[(128 + b) * 5 + f];
  }
  float m = fmaxf(w0, fmaxf(w1, w2));
  float e0 = __expf(w0 - m), e1 = __expf(w1 - m), e2 = __expf(w2 - m);
  float inv = 1.0f / (e0 + e1 + e2);
  e0 *= inv; e1 *= inv; e2 *= inv;
  size_t base = (size_t)bv * 256 + c8;
  const size_t V1 = (size_t)64 * VN * 256, V2 = (size_t)128 * VN * 256;
  floatx4 x0a = *(const floatx4*)(x + base);
  floatx4 x0b = *(const floatx4*)(x + base + 4);
  floatx4 x1a = *(const floatx4*)(x + V1 + base);
  floatx4 x1b = *(const floatx4*)(x + V1 + base + 4);
  floatx4 x2a = *(const floatx4*)(x + V2 + base);
  floatx4 x2b = *(const floatx4*)(x + V2 + base + 4);
  ushort8 o, xo;
#pragma unroll
  for (int e = 0; e < 4; ++e) {
    o[e]     = f2bf(e0 * x0a[e] + e1 * x1a[e] + e2 * x2a[e]);
    o[e + 4] = f2bf(e0 * x0b[e] + e1 * x1b[e] + e2 * x2b[e]);
    xo[e]     = f2bf(x0a[e]);
    xo[e + 4] = f2bf(x0b[e]);
  }
  *(ushort8*)(wx + base) = o;
  if (xb) *(ushort8*)(xb + base) = xo;
}

// ---------------- pack W[k][n] (f32) into bf16 MFMA B-fragment order --------
// strip-major: chunk = ((n/32)*(Ktot/16) + k/16)*64 + ((k%16)/8)*32 + (n%32).
// All three weight matrices packed in ONE launch (range dispatch).
__global__ void pack_all(const float* __restrict__ w0, const float* __restrict__ w1,
                         const float* __restrict__ w2, ushort_t* __restrict__ wP0,
                         ushort_t* __restrict__ wP1, ushort_t* __restrict__ wP2) {
  int chunk = blockIdx.x * 256 + threadIdx.x;  // 0 .. 516095 (exact)
  const float* w; ushort_t* wP; int N, ksn;
  if (chunk < 294912)       { w = w0; wP = wP0; N = 512; ksn = 288; }
  else if (chunk < 442368)  { chunk -= 294912; w = w1; wP = wP1; N = 256; ksn = 288; }
  else                      { chunk -= 442368; w = w2; wP = wP2; N = 256; ksn = 144; }
  int lane = chunk & 63;
  int rest = chunk >> 6;
  int ks = rest % ksn;
  int tn = rest / ksn;
  int n = (tn << 5) + (lane & 31);
  int kb = (ks << 4) + ((lane >> 5) << 3);
  ushort8 o;
#pragma unroll
  for (int j = 0; j < 8; ++j) o[j] = f2bf(w[(size_t)(kb + j) * N + n]);
  *(ushort8*)(wP + (size_t)chunk * 8) = o;
}

// ---------------- spiral gathered GEMM (round-0 proven structure) -----------
// block = 2 vertices, 512 threads (8 waves); wave tile = 128m(2v x 64b) x 32n.
// 1 B-load per 4 MFMA (m=128/wave is the B-amortization sweet spot — R1/R5
// showed halving it costs more than any makespan gain). A double-buffered in
// 128-ch phases (2 x 32 KB LDS), staged by global_load_lds DMA, swizzle on the
// SOURCE side; ONE barrier per phase. 64 VGPR + 64 AGPR = 128 regs/wave ->
// 16 waves/CU (2 blocks) — the proven latency-hiding regime.
// MODE 0: single bf16 act (rowstride CIN). MODE 1: wx bf16 + x f32 (f32
// phases staged synchronously). MODE 2: wx bf16 + pre-converted bf16 xb.
template <int CIN, int MODE>
__global__ __launch_bounds__(512, 4) void spiral_gemm(
    const ushort_t* __restrict__ act0, const float* __restrict__ actF,
    const ushort_t* __restrict__ actB, const ushort_t* __restrict__ wP,
    const float* __restrict__ bias, const int* __restrict__ idx,
    ushort_t* __restrict__ out, int NOUT, int nbx) {
  constexpr int H = CIN / 128;       // 128-ch phases per neighbor
  constexpr int P = KNB * H;
  __shared__ __align__(16) ushort_t Alds[2][2048 * 8];   // 2 x 32 KB
  const int wgid = xcd_swizzle(blockIdx.x, gridDim.x);
  const int yb = wgid / nbx;
  const int xb = wgid - yb * nbx;
  const int v0 = xb * 2;
  const int n0 = yb << 8;
  const int tid = threadIdx.x;
  const int lane = tid & 63;
  const int wv = tid >> 6;           // n-strip (0..7)
  const int mlo = lane & 31;
  const int q = lane >> 5;
  const int xm = mlo & 7;
  floatx16 acc0{}, acc1{}, acc2{}, acc3{};
  const int KtotSteps = KNB * (CIN / 16);
  const int tn0 = (n0 >> 5) + wv;
  const ushort_t* bp = wP + (size_t)tn0 * KtotSteps * 512 + lane * 8;
  const int* iv0 = idx + v0 * KNB;
  const int* iv1 = iv0 + KNB;
  const int aoff0 = mlo * 128;
  const int aoff1 = (mlo + 32) * 128;
  const int aoff2 = 8192 + mlo * 128;
  const int aoff3 = 8192 + (mlo + 32) * 128;

  auto dma_stage = [&](int p, ushort_t* buf) {  // bf16 phases only
    const int nbr = p / H, h = p - nbr * H;
    const int nva = iv0[nbr], nvb = iv1[nbr];
#pragma unroll
    for (int it = 0; it < 4; ++it) {
      const int slotb = ((wv << 2) + it) << 6;   // wave-uniform slot base
      const int s = slotb + lane;
      const int vv = s >> 10;
      const int row = (s >> 4) & 63;
      const int ck = (s & 15) ^ (row & 7);       // swizzle on source side
      const int nv = vv ? nvb : nva;
      const ushort_t* src;
      if (MODE == 0) {
        src = act0 + ((size_t)(row * VN + nv)) * CIN + h * 128 + ck * 8;
      } else {
        const ushort_t* basep = (MODE == 1 || h < 2) ? act0 : actB;
        src = basep + ((size_t)(row * VN + nv)) * 256 + (h & 1) * 128 + ck * 8;
      }
      load_lds16(src, buf + (size_t)slotb * 8);
    }
  };
  auto f32_stage = [&](int p, ushort_t* buf) {  // MODE 1, h in {2,3}
    const int nbr = p / H, h = p - nbr * H;
    const int nva = iv0[nbr], nvb = iv1[nbr];
#pragma unroll
    for (int j = 0; j < 4; ++j) {
      const int s = (j << 9) + tid;
      const int vv = s >> 10;
      const int row = (s >> 4) & 63;
      const int ck = (s & 15) ^ (row & 7);
      const int nv = vv ? nvb : nva;
      const float* src = actF + ((size_t)(row * VN + nv)) * 256 + (h - 2) * 128 + ck * 8;
      floatx4 fa = *(const floatx4*)src;
      floatx4 fb = *(const floatx4*)(src + 4);
      ushort8 o;
#pragma unroll
      for (int e = 0; e < 4; ++e) { o[e] = f2bf(fa[e]); o[e + 4] = f2bf(fb[e]); }
      *(ushort8*)(buf + (size_t)s * 8) = o;
    }
  };

  dma_stage(0, Alds[0]);   // phase 0 is always bf16 (h=0)
  __syncthreads();
#pragma unroll 2
  for (int p = 0; p < P; ++p) {
    ushort_t* cur = Alds[p & 1];
    ushort_t* nxt = Alds[(p + 1) & 1];
    const bool have_next = (p + 1 < P);
    const bool next_f32 = (MODE == 1) && (((p + 1) & (H - 1)) >= 2);
    if (have_next && !next_f32) dma_stage(p + 1, nxt);
#pragma unroll
    for (int ks = 0; ks < 8; ++ks) {
      const int cko = ((((ks << 1) + q) ^ xm) << 3);
      bf16x8 a0 = *(const bf16x8*)(cur + aoff0 + cko);
      bf16x8 a1 = *(const bf16x8*)(cur + aoff1 + cko);
      bf16x8 a2 = *(const bf16x8*)(cur + aoff2 + cko);
      bf16x8 a3 = *(const bf16x8*)(cur + aoff3 + cko);
      bf16x8 bv = *(const bf16x8*)bp; bp += 512;
      acc0 = __builtin_amdgcn_mfma_f32_32x32x16_bf16(a0, bv, acc0, 0, 0, 0);
      acc1 = __builtin_amdgcn_mfma_f32_32x32x16_bf16(a1, bv, acc1, 0, 0, 0);
      acc2 = __builtin_amdgcn_mfma_f32_32x32x16_bf16(a2, bv, acc2, 0, 0, 0);
      acc3 = __builtin_amdgcn_mfma_f32_32x32x16_bf16(a3, bv, acc3, 0, 0, 0);
    }
    __syncthreads();   // drains DMA vmcnt; all waves done reading cur
    if (have_next && next_f32) { f32_stage(p + 1, nxt); __syncthreads(); }
  }
  // epilogue: C/D layout col=lane&31 (=n), row=(reg&3)+8*(reg>>2)+4*(lane>>5)
  const int n = n0 + (wv << 5) + mlo;
  const float bn = bias[n];
#pragma unroll
  for (int t = 0; t < 4; ++t) {
    const floatx16 av = (t == 0) ? acc0 : (t == 1) ? acc1 : (t == 2) ? acc2 : acc3;
    const int vcur = v0 + (t >> 1);
    const int bbase = (t & 1) << 5;
#pragma unroll
    for (int r = 0; r < 16; ++r) {
      const int m = (r & 3) + ((r >> 2) << 3) + (q << 2);
      float val = av[r] + bn; val = val > 0.f ? val : 0.f;
      out[((size_t)((bbase + m) * VN + vcur)) * NOUT + n] = f2bf(val);
    }
  }
}

// ---------------- head: gathered [64 x 2304] @ [2304 x 3], f32 out ---------
// All 256 threads active in compute: thread (b, kc) = (tid&63, tid>>6) handles
// k-chunk kc (8 of 32 j-blocks) for batch b; 4 partials LDS-reduced at the end.
__global__ void head_kernel(const ushort_t* __restrict__ act, const float* __restrict__ whT,
                            const float* __restrict__ bh, const int* __restrict__ idx,
                            float* __restrict__ out) {
  __shared__ __align__(16) ushort_t Alds[64 * 256];
  __shared__ float red[3][4][64];
  const int v = xcd_swizzle(blockIdx.x, gridDim.x);
  const int tid = threadIdx.x;
  const int b = tid & 63;
  const int kc = tid >> 6;    // 0..3: j-range [kc*8, kc*8+8)
  const int xm = b & 7;
  float a0 = 0.f, a1 = 0.f, a2 = 0.f;
  for (int nbr = 0; nbr < KNB; ++nbr) {
    const int nv = idx[v * KNB + nbr];
    __syncthreads();
#pragma unroll
    for (int it = 0; it < 8; ++it) {
      int L = it * 256 + tid;
      int bb = L >> 5;
      int jj = L & 31;
      ushort8 val = *(const ushort8*)(act + ((size_t)(bb * VN + nv)) * 256 + (jj << 3));
      int slot = jj ^ (bb & 7);
      *(ushort8*)&Alds[(size_t)(bb * 32 + slot) * 8] = val;
    }
    __syncthreads();
    const float* wp = whT + nbr * 256;
#pragma unroll
    for (int j0 = 0; j0 < 8; ++j0) {
      int j = (kc << 3) + j0;
      int jj = j ^ xm;             // stays within the 8-aligned chunk
      ushort8 a8 = *(const ushort8*)&Alds[(b * 32 + jj) * 8];
#pragma unroll
      for (int e = 0; e < 8; ++e) {
        float av = bf2f(a8[e]);
        int k = (j << 3) + e;
        a0 += av * wp[k];
        a1 += av * wp[2304 + k];
        a2 += av * wp[4608 + k];
      }
    }
  }
  red[0][kc][b] = a0;
  red[1][kc][b] = a1;
  red[2][kc][b] = a2;
  __syncthreads();
  if (tid < 64) {
    float s0 = red[0][0][b] + red[0][1][b] + red[0][2][b] + red[0][3][b];
    float s1 = red[1][0][b] + red[1][1][b] + red[1][2][b] + red[1][3][b];
    float s2 = red[2][0][b] + red[2][1][b] + red[2][2][b] + red[2][3][b];
    size_t o = ((size_t)(b * VN + v)) * 3;
    out[o + 0] = s0 + bh[0];
    out[o + 1] = s1 + bh[1];
    out[o + 2] = s2 + bh[2];
  }
}

extern "C" void kernel_launch(void* const* d_in, const int* in_sizes, int n_in,
                              void* d_out, int out_size, void* d_ws, size_t ws_size,
                              hipStream_t stream) {
  const float* x        = (const float*)d_in[0];
  const float* pred_occ = (const float*)d_in[1];
  const int* indices    = (const int*)d_in[2];
  const int* f0 = (const int*)d_in[3];
  const int* f1 = (const int*)d_in[4];
  const int* f2 = (const int*)d_in[5];
  const int* f3 = (const int*)d_in[6];
  const int* f4 = (const int*)d_in[7];
  const float* w0 = (const float*)d_in[8];
  const float* b0 = (const float*)d_in[9];
  const float* w1 = (const float*)d_in[10];
  const float* b1 = (const float*)d_in[11];
  const float* w2 = (const float*)d_in[12];
  const float* b2 = (const float*)d_in[13];
  const float* wh = (const float*)d_in[14];
  const float* bh = (const float*)d_in[15];
  float* outp = (float*)d_out;

  char* ws = (char*)d_ws;
  ushort_t* wP0 = (ushort_t*)(ws + 0);         // 512 x 4608 bf16 (4,718,592 B)
  ushort_t* wP1 = (ushort_t*)(ws + 4718592);   // 256 x 4608 bf16 (2,359,296 B)
  ushort_t* wP2 = (ushort_t*)(ws + 7077888);   // 256 x 2304 bf16 (1,179,648 B)
  float* whT    = (float*)(ws + 8257536);      // 3 x 2304 f32
  float* occ    = (float*)(ws + 8285184);      // 192 x 5 f32
  int* fid      = (int*)(ws + 8289024);        // 778 i32
  ushort_t* R0  = (ushort_t*)(ws + 8292352);   // wx, later h2   [64,V,256] 25.5MB
  ushort_t* R1  = (ushort_t*)(ws + 33785856);  // h1, later h3   [64,V,512] 51MB
  ushort_t* XB  = (ushort_t*)(ws + 84772864);  // optional bf16 x view0, 25.5MB
  const bool useXB = (ws_size >= 110266368ull);

  prep_misc<<<1, 256, 0, stream>>>(pred_occ, f0, f1, f2, f3, f4,
                                   in_sizes[3], in_sizes[4], in_sizes[5],
                                   in_sizes[6], in_sizes[7], wh, occ, fid, whT);
  pack_all<<<516096 / 256, 256, 0, stream>>>(w0, w1, w2, wP0, wP1, wP2);
  wx_kernel<<<6224, 256, 0, stream>>>(x, occ, fid, R0, useXB ? XB : nullptr);

  // conv0: [wx | x_view0] (512ch) -> h1 (512ch bf16); 1-D grid 778 = 389x * 2y,
  // XCD swizzle keeps each B half-panel resident in one XCD group's L2.
  if (useXB)
    spiral_gemm<512, 2><<<778, 512, 0, stream>>>(R0, nullptr, XB, wP0, b0,
                                                 indices, R1, 512, 389);
  else
    spiral_gemm<512, 1><<<778, 512, 0, stream>>>(R0, x, nullptr, wP0, b0,
                                                 indices, R1, 512, 389);
  // conv1: h1 (512ch) -> h2 (256ch)
  spiral_gemm<512, 0><<<389, 512, 0, stream>>>(R1, nullptr, nullptr, wP1, b1,
                                               indices, R0, 256, 389);
  // conv2: h2 (256ch) -> h3 (256ch)
  spiral_gemm<256, 0><<<389, 512, 0, stream>>>(R0, nullptr, nullptr, wP2, b2,
                                               indices, R1, 256, 389);
  // head: h3 -> out [64,V,3] f32
  head_kernel<<<VN, 256, 0, stream>>>(R1, whT, bh, indices, outp);
  (void)n_in; (void)out_size;
}

// Round 8
// 806.870 us; speedup vs baseline: 1.1332x; 1.0027x over previous
//
#include <hip/hip_runtime.h>

typedef unsigned short ushort_t;
typedef __attribute__((ext_vector_type(8))) __bf16 bf16x8;
typedef __attribute__((ext_vector_type(8))) unsigned short ushort8;
typedef __attribute__((ext_vector_type(4))) float floatx4;
typedef __attribute__((ext_vector_type(16))) float floatx16;

#define VN 778
#define KNB 9

__device__ __forceinline__ float bf2f(unsigned short s) {
  union { unsigned int u; float f; } x; x.u = ((unsigned int)s) << 16; return x.f;
}
__device__ __forceinline__ unsigned short f2bf(float f) {
  union { float f; unsigned int u; } x; x.f = f;
  unsigned int r = x.u + 0x7fffu + ((x.u >> 16) & 1u);
  return (unsigned short)(r >> 16);
}

// async global -> LDS, 16B per lane; LDS dest = wave-uniform base + lane*16.
__device__ __forceinline__ void load_lds16(const void* g, void* l) {
  __builtin_amdgcn_global_load_lds(
      (const __attribute__((address_space(1))) unsigned int*)g,
      (__attribute__((address_space(3))) unsigned int*)l, 16, 0, 0);
}

// Bijective XCD-aware swizzle (m204 form): XCD k gets a contiguous wgid range.
__device__ __forceinline__ int xcd_swizzle(int g, int nwg) {
  int q = nwg >> 3, r = nwg & 7;
  int xcd = g & 7, o = g >> 3;
  return (xcd < r ? xcd * (q + 1) : r * (q + 1) + (xcd - r) * q) + o;
}

// ---------------- prologue: occ probabilities, finger ids, wh transpose ----
__global__ void prep_misc(const float* __restrict__ pred_occ,
                          const int* f0, const int* f1, const int* f2,
                          const int* f3, const int* f4,
                          int n0, int n1, int n2, int n3, int n4,
                          const float* __restrict__ wh,
                          float* __restrict__ occ, int* __restrict__ fid,
                          float* __restrict__ whT) {
  int t = threadIdx.x;
  for (int i = t; i < 192 * 5; i += 256) {
    int r = i / 5, f = i % 5;
    float p0 = pred_occ[r * 10 + f];
    float p1 = pred_occ[r * 10 + 5 + f];
    occ[i] = 1.0f / (1.0f + __expf(p1 - p0));  // softmax over 2 classes, class 0
  }
  for (int i = t; i < VN; i += 256) fid[i] = -1;
  __syncthreads();
  const int* fp[5] = {f0, f1, f2, f3, f4};
  int fn[5] = {n0, n1, n2, n3, n4};
  for (int fi = 0; fi < 5; ++fi) {  // sequential: later fingers overwrite
    for (int i = t; i < fn[fi]; i += 256) fid[fp[fi][i]] = fi;
    __syncthreads();
  }
  for (int i = t; i < 3 * 2304; i += 256) {
    int o = i / 2304, k = i % 2304;
    whT[i] = wh[k * 3 + o];
  }
}

// ---------------- weighted view mix + fused view-0 bf16 copy ----------------
// wx/xb are written VERTEX-MAJOR [v][64][256]: one vertex's 64 batch-rows are
// contiguous (32 KB), so the conv gathers read contiguous blocks (L2-reusable)
// instead of 64 rows strided 398 KB apart (the 9x uncached re-read seen as
// FETCH_SIZE = 452 MB in rounds 0-7).
__global__ void wx_kernel(const float* __restrict__ x, const float* __restrict__ occ,
                          const int* __restrict__ fid, ushort_t* __restrict__ wx,
                          ushort_t* __restrict__ xb) {
  int g = blockIdx.x * 256 + threadIdx.x;  // 8-ch chunk id over 64*778*32 (exact)
  int c8 = (g & 31) << 3;
  int bv = g >> 5;
  int b = bv / VN;
  int v = bv - b * VN;
  int f = fid[v];
  float w0 = 1.f, w1 = 1.f, w2 = 1.f;
  if (f >= 0) {
    w0 = occ[b * 5 + f];
    w1 = occ[(64 + b) * 5 + f];
    w2 = occ[(128 + b) * 5 + f];
  }
  float m = fmaxf(w0, fmaxf(w1, w2));
  float e0 = __expf(w0 - m), e1 = __expf(w1 - m), e2 = __expf(w2 - m);
  float inv = 1.0f / (e0 + e1 + e2);
  e0 *= inv; e1 *= inv; e2 *= inv;
  size_t base = (size_t)bv * 256 + c8;                 // x is batch-major (input)
  size_t obase = ((size_t)(v * 64 + b)) * 256 + c8;    // vertex-major out
  const size_t V1 = (size_t)64 * VN * 256, V2 = (size_t)128 * VN * 256;
  floatx4 x0a = *(const floatx4*)(x + base);
  floatx4 x0b = *(const floatx4*)(x + base + 4);
  floatx4 x1a = *(const floatx4*)(x + V1 + base);
  floatx4 x1b = *(const floatx4*)(x + V1 + base + 4);
  floatx4 x2a = *(const floatx4*)(x + V2 + base);
  floatx4 x2b = *(const floatx4*)(x + V2 + base + 4);
  ushort8 o, xo;
#pragma unroll
  for (int e = 0; e < 4; ++e) {
    o[e]     = f2bf(e0 * x0a[e] + e1 * x1a[e] + e2 * x2a[e]);
    o[e + 4] = f2bf(e0 * x0b[e] + e1 * x1b[e] + e2 * x2b[e]);
    xo[e]     = f2bf(x0a[e]);
    xo[e + 4] = f2bf(x0b[e]);
  }
  *(ushort8*)(wx + obase) = o;
  if (xb) *(ushort8*)(xb + obase) = xo;
}

// ---------------- pack W[k][n] (f32) into bf16 MFMA B-fragment order --------
// strip-major: chunk = ((n/32)*(Ktot/16) + k/16)*64 + ((k%16)/8)*32 + (n%32).
// All three weight matrices packed in ONE launch (range dispatch).
__global__ void pack_all(const float* __restrict__ w0, const float* __restrict__ w1,
                         const float* __restrict__ w2, ushort_t* __restrict__ wP0,
                         ushort_t* __restrict__ wP1, ushort_t* __restrict__ wP2) {
  int chunk = blockIdx.x * 256 + threadIdx.x;  // 0 .. 516095 (exact)
  const float* w; ushort_t* wP; int N, ksn;
  if (chunk < 294912)       { w = w0; wP = wP0; N = 512; ksn = 288; }
  else if (chunk < 442368)  { chunk -= 294912; w = w1; wP = wP1; N = 256; ksn = 288; }
  else                      { chunk -= 442368; w = w2; wP = wP2; N = 256; ksn = 144; }
  int lane = chunk & 63;
  int rest = chunk >> 6;
  int ks = rest % ksn;
  int tn = rest / ksn;
  int n = (tn << 5) + (lane & 31);
  int kb = (ks << 4) + ((lane >> 5) << 3);
  ushort8 o;
#pragma unroll
  for (int j = 0; j < 8; ++j) o[j] = f2bf(w[(size_t)(kb + j) * N + n]);
  *(ushort8*)(wP + (size_t)chunk * 8) = o;
}

// ---------------- spiral gathered GEMM (round-0 proven structure) -----------
// block = 2 vertices, 512 threads (8 waves); wave tile = 128m(2v x 64b) x 32n.
// A double-buffered in 128-ch phases (2 x 32 KB LDS), staged by global_load_lds
// DMA, swizzle on SOURCE side; ONE barrier per phase; 16 waves/CU.
// Intermediate activations (act0/actB and out when NOUT!=3) are VERTEX-MAJOR
// [v][64][C]: a neighbor's staged slice is one contiguous 16 KB block, each
// DMA instruction reads a contiguous 4 KB chunk, and same-XCD blocks (contiguous
// vertex ranges via the swizzle) gather overlapping mesh-local neighbor sets.
// MODE 0: single bf16 act. MODE 1: wx bf16 + x f32 (x stays batch-major, staged
// synchronously). MODE 2: wx bf16 + pre-converted bf16 xb.
template <int CIN, int MODE>
__global__ __launch_bounds__(512, 4) void spiral_gemm(
    const ushort_t* __restrict__ act0, const float* __restrict__ actF,
    const ushort_t* __restrict__ actB, const ushort_t* __restrict__ wP,
    const float* __restrict__ bias, const int* __restrict__ idx,
    ushort_t* __restrict__ out, int NOUT, int nbx) {
  constexpr int H = CIN / 128;       // 128-ch phases per neighbor
  constexpr int P = KNB * H;
  __shared__ __align__(16) ushort_t Alds[2][2048 * 8];   // 2 x 32 KB
  const int wgid = xcd_swizzle(blockIdx.x, gridDim.x);
  const int yb = wgid / nbx;
  const int xb = wgid - yb * nbx;
  const int v0 = xb * 2;
  const int n0 = yb << 8;
  const int tid = threadIdx.x;
  const int lane = tid & 63;
  const int wv = tid >> 6;           // n-strip (0..7)
  const int mlo = lane & 31;
  const int q = lane >> 5;
  const int xm = mlo & 7;
  floatx16 acc0{}, acc1{}, acc2{}, acc3{};
  const int KtotSteps = KNB * (CIN / 16);
  const int tn0 = (n0 >> 5) + wv;
  const ushort_t* bp = wP + (size_t)tn0 * KtotSteps * 512 + lane * 8;
  const int* iv0 = idx + v0 * KNB;
  const int* iv1 = iv0 + KNB;
  const int aoff0 = mlo * 128;
  const int aoff1 = (mlo + 32) * 128;
  const int aoff2 = 8192 + mlo * 128;
  const int aoff3 = 8192 + (mlo + 32) * 128;

  auto dma_stage = [&](int p, ushort_t* buf) {  // bf16 phases only
    const int nbr = p / H, h = p - nbr * H;
    const int nva = iv0[nbr], nvb = iv1[nbr];
#pragma unroll
    for (int it = 0; it < 4; ++it) {
      const int slotb = ((wv << 2) + it) << 6;   // wave-uniform slot base
      const int s = slotb + lane;
      const int vv = s >> 10;
      const int row = (s >> 4) & 63;
      const int ck = (s & 15) ^ (row & 7);       // swizzle on source side
      const int nv = vv ? nvb : nva;
      const ushort_t* src;
      if (MODE == 0) {
        src = act0 + ((size_t)(nv * 64 + row)) * CIN + h * 128 + ck * 8;
      } else {
        const ushort_t* basep = (MODE == 1 || h < 2) ? act0 : actB;
        src = basep + ((size_t)(nv * 64 + row)) * 256 + (h & 1) * 128 + ck * 8;
      }
      load_lds16(src, buf + (size_t)slotb * 8);
    }
  };
  auto f32_stage = [&](int p, ushort_t* buf) {  // MODE 1, h in {2,3}; x batch-major
    const int nbr = p / H, h = p - nbr * H;
    const int nva = iv0[nbr], nvb = iv1[nbr];
#pragma unroll
    for (int j = 0; j < 4; ++j) {
      const int s = (j << 9) + tid;
      const int vv = s >> 10;
      const int row = (s >> 4) & 63;
      const int ck = (s & 15) ^ (row & 7);
      const int nv = vv ? nvb : nva;
      const float* src = actF + ((size_t)(row * VN + nv)) * 256 + (h - 2) * 128 + ck * 8;
      floatx4 fa = *(const floatx4*)src;
      floatx4 fb = *(const floatx4*)(src + 4);
      ushort8 o;
#pragma unroll
      for (int e = 0; e < 4; ++e) { o[e] = f2bf(fa[e]); o[e + 4] = f2bf(fb[e]); }
      *(ushort8*)(buf + (size_t)s * 8) = o;
    }
  };

  dma_stage(0, Alds[0]);   // phase 0 is always bf16 (h=0)
  __syncthreads();
#pragma unroll 2
  for (int p = 0; p < P; ++p) {
    ushort_t* cur = Alds[p & 1];
    ushort_t* nxt = Alds[(p + 1) & 1];
    const bool have_next = (p + 1 < P);
    const bool next_f32 = (MODE == 1) && (((p + 1) & (H - 1)) >= 2);
    if (have_next && !next_f32) dma_stage(p + 1, nxt);
#pragma unroll
    for (int ks = 0; ks < 8; ++ks) {
      const int cko = ((((ks << 1) + q) ^ xm) << 3);
      bf16x8 a0 = *(const bf16x8*)(cur + aoff0 + cko);
      bf16x8 a1 = *(const bf16x8*)(cur + aoff1 + cko);
      bf16x8 a2 = *(const bf16x8*)(cur + aoff2 + cko);
      bf16x8 a3 = *(const bf16x8*)(cur + aoff3 + cko);
      bf16x8 bv = *(const bf16x8*)bp; bp += 512;
      acc0 = __builtin_amdgcn_mfma_f32_32x32x16_bf16(a0, bv, acc0, 0, 0, 0);
      acc1 = __builtin_amdgcn_mfma_f32_32x32x16_bf16(a1, bv, acc1, 0, 0, 0);
      acc2 = __builtin_amdgcn_mfma_f32_32x32x16_bf16(a2, bv, acc2, 0, 0, 0);
      acc3 = __builtin_amdgcn_mfma_f32_32x32x16_bf16(a3, bv, acc3, 0, 0, 0);
    }
    __syncthreads();   // drains DMA vmcnt; all waves done reading cur
    if (have_next && next_f32) { f32_stage(p + 1, nxt); __syncthreads(); }
  }
  // epilogue: C/D layout col=lane&31 (=n), row=(reg&3)+8*(reg>>2)+4*(lane>>5).
  // Intermediate outputs are vertex-major [v][64][NOUT].
  const int n = n0 + (wv << 5) + mlo;
  const float bn = bias[n];
#pragma unroll
  for (int t = 0; t < 4; ++t) {
    const floatx16 av = (t == 0) ? acc0 : (t == 1) ? acc1 : (t == 2) ? acc2 : acc3;
    const int vcur = v0 + (t >> 1);
    const int bbase = (t & 1) << 5;
#pragma unroll
    for (int r = 0; r < 16; ++r) {
      const int m = (r & 3) + ((r >> 2) << 3) + (q << 2);
      float val = av[r] + bn; val = val > 0.f ? val : 0.f;
      out[((size_t)(vcur * 64 + bbase + m)) * NOUT + n] = f2bf(val);
    }
  }
}

// ---------------- head: gathered [64 x 2304] @ [2304 x 3], f32 out ---------
// act (h3) is vertex-major: each neighbor read is one contiguous 32 KB block.
// All 256 threads active in compute: thread (b, kc) = (tid&63, tid>>6) handles
// k-chunk kc (8 of 32 j-blocks) for batch b; 4 partials LDS-reduced at the end.
__global__ void head_kernel(const ushort_t* __restrict__ act, const float* __restrict__ whT,
                            const float* __restrict__ bh, const int* __restrict__ idx,
                            float* __restrict__ out) {
  __shared__ __align__(16) ushort_t Alds[64 * 256];
  __shared__ float red[3][4][64];
  const int v = xcd_swizzle(blockIdx.x, gridDim.x);
  const int tid = threadIdx.x;
  const int b = tid & 63;
  const int kc = tid >> 6;    // 0..3: j-range [kc*8, kc*8+8)
  const int xm = b & 7;
  float a0 = 0.f, a1 = 0.f, a2 = 0.f;
  for (int nbr = 0; nbr < KNB; ++nbr) {
    const int nv = idx[v * KNB + nbr];
    __syncthreads();
#pragma unroll
    for (int it = 0; it < 8; ++it) {
      int L = it * 256 + tid;
      int bb = L >> 5;
      int jj = L & 31;
      ushort8 val = *(const ushort8*)(act + ((size_t)(nv * 64 + bb)) * 256 + (jj << 3));
      int slot = jj ^ (bb & 7);
      *(ushort8*)&Alds[(size_t)(bb * 32 + slot) * 8] = val;
    }
    __syncthreads();
    const float* wp = whT + nbr * 256;
#pragma unroll
    for (int j0 = 0; j0 < 8; ++j0) {
      int j = (kc << 3) + j0;
      int jj = j ^ xm;             // stays within the 8-aligned chunk
      ushort8 a8 = *(const ushort8*)&Alds[(b * 32 + jj) * 8];
#pragma unroll
      for (int e = 0; e < 8; ++e) {
        float av = bf2f(a8[e]);
        int k = (j << 3) + e;
        a0 += av * wp[k];
        a1 += av * wp[2304 + k];
        a2 += av * wp[4608 + k];
      }
    }
  }
  red[0][kc][b] = a0;
  red[1][kc][b] = a1;
  red[2][kc][b] = a2;
  __syncthreads();
  if (tid < 64) {
    float s0 = red[0][0][b] + red[0][1][b] + red[0][2][b] + red[0][3][b];
    float s1 = red[1][0][b] + red[1][1][b] + red[1][2][b] + red[1][3][b];
    float s2 = red[2][0][b] + red[2][1][b] + red[2][2][b] + red[2][3][b];
    size_t o = ((size_t)(b * VN + v)) * 3;   // final output stays batch-major
    out[o + 0] = s0 + bh[0];
    out[o + 1] = s1 + bh[1];
    out[o + 2] = s2 + bh[2];
  }
}

extern "C" void kernel_launch(void* const* d_in, const int* in_sizes, int n_in,
                              void* d_out, int out_size, void* d_ws, size_t ws_size,
                              hipStream_t stream) {
  const float* x        = (const float*)d_in[0];
  const float* pred_occ = (const float*)d_in[1];
  const int* indices    = (const int*)d_in[2];
  const int* f0 = (const int*)d_in[3];
  const int* f1 = (const int*)d_in[4];
  const int* f2 = (const int*)d_in[5];
  const int* f3 = (const int*)d_in[6];
  const int* f4 = (const int*)d_in[7];
  const float* w0 = (const float*)d_in[8];
  const float* b0 = (const float*)d_in[9];
  const float* w1 = (const float*)d_in[10];
  const float* b1 = (const float*)d_in[11];
  const float* w2 = (const float*)d_in[12];
  const float* b2 = (const float*)d_in[13];
  const float* wh = (const float*)d_in[14];
  const float* bh = (const float*)d_in[15];
  float* outp = (float*)d_out;

  char* ws = (char*)d_ws;
  ushort_t* wP0 = (ushort_t*)(ws + 0);         // 512 x 4608 bf16 (4,718,592 B)
  ushort_t* wP1 = (ushort_t*)(ws + 4718592);   // 256 x 4608 bf16 (2,359,296 B)
  ushort_t* wP2 = (ushort_t*)(ws + 7077888);   // 256 x 2304 bf16 (1,179,648 B)
  float* whT    = (float*)(ws + 8257536);      // 3 x 2304 f32
  float* occ    = (float*)(ws + 8285184);      // 192 x 5 f32
  int* fid      = (int*)(ws + 8289024);        // 778 i32
  ushort_t* R0  = (ushort_t*)(ws + 8292352);   // wx, later h2   [V,64,256] 25.5MB
  ushort_t* R1  = (ushort_t*)(ws + 33785856);  // h1, later h3   [V,64,512] 51MB
  ushort_t* XB  = (ushort_t*)(ws + 84772864);  // optional bf16 x view0, 25.5MB
  const bool useXB = (ws_size >= 110266368ull);

  prep_misc<<<1, 256, 0, stream>>>(pred_occ, f0, f1, f2, f3, f4,
                                   in_sizes[3], in_sizes[4], in_sizes[5],
                                   in_sizes[6], in_sizes[7], wh, occ, fid, whT);
  pack_all<<<516096 / 256, 256, 0, stream>>>(w0, w1, w2, wP0, wP1, wP2);
  wx_kernel<<<6224, 256, 0, stream>>>(x, occ, fid, R0, useXB ? XB : nullptr);

  // conv0: [wx | x_view0] (512ch) -> h1 (512ch bf16); 1-D grid 778 = 389x * 2y,
  // XCD swizzle keeps contiguous vertex ranges (and one B half-panel) per XCD.
  if (useXB)
    spiral_gemm<512, 2><<<778, 512, 0, stream>>>(R0, nullptr, XB, wP0, b0,
                                                 indices, R1, 512, 389);
  else
    spiral_gemm<512, 1><<<778, 512, 0, stream>>>(R0, x, nullptr, wP0, b0,
                                                 indices, R1, 512, 389);
  // conv1: h1 (512ch) -> h2 (256ch)
  spiral_gemm<512, 0><<<389, 512, 0, stream>>>(R1, nullptr, nullptr, wP1, b1,
                                               indices, R0, 256, 389);
  // conv2: h2 (256ch) -> h3 (256ch)
  spiral_gemm<256, 0><<<389, 512, 0, stream>>>(R0, nullptr, nullptr, wP2, b2,
                                               indices, R1, 256, 389);
  // head: h3 -> out [64,V,3] f32
  head_kernel<<<VN, 256, 0, stream>>>(R1, whT, bh, indices, outp);
  (void)n_in; (void)out_size;
}